// Round 8
// baseline (915.666 us; speedup 1.0000x reference)
//
#include <hip/hip_runtime.h>

// Fused RNN: encoders + 576-step LSTM + projection + softmax.
// 256 blocks x 512 threads, 4 batches/block, 1 block/CU.
//
// Round-8 = Round-6 structure (best: 787us) + two latency fixes:
//  (1) staging raw input rows prefetched into ping-pong REGISTERS 2 steps deep
//      (row t+3 issued at step t, consumed at step t+2): the 9 global loads'
//      latency (L2 ~250 / HBM ~900 cyc) leaves the phase-2 barrier path.
//  (2) wave-7 projection split into 4 independent dot2 accumulators
//      (serial chain 50 -> 13).
// Everything else byte-identical to round 6 (MFMA -> Z -> 400-thread act).

#define NTHR 512

typedef _Float16 half8 __attribute__((ext_vector_type(8)));
typedef _Float16 h2    __attribute__((ext_vector_type(2)));
typedef _Float16 h4v   __attribute__((ext_vector_type(4)));
typedef _Float16 h8v   __attribute__((ext_vector_type(8)));
typedef float    f32x4 __attribute__((ext_vector_type(4)));

struct __align__(16) SM {
  _Float16 Y[2][16][136];  // [phase][m(batch,4 used)][k]: h(0..99), s(100..108), 1(109), 0 pad
  float Z[400][4];         // [n][batch] gate pre-activations
  float w_in[81], w_task[81];
  float b_in[9], b_task[9];
};

__device__ __forceinline__ float dot2(h2 a, h2 b, float c) {
#if defined(__has_builtin)
#if __has_builtin(__builtin_amdgcn_fdot2)
  return __builtin_amdgcn_fdot2(a, b, c, false);
#else
  return fmaf((float)a.x, (float)b.x, fmaf((float)a.y, (float)b.y, c));
#endif
#else
  return fmaf((float)a.x, (float)b.x, fmaf((float)a.y, (float)b.y, c));
#endif
}

__device__ __forceinline__ float fast_sigmoid(float x) {
  return __builtin_amdgcn_rcpf(1.f + __expf(-x));
}
__device__ __forceinline__ float fast_tanh(float x) {
  return fmaf(2.f, __builtin_amdgcn_rcpf(1.f + __expf(-2.f * x)), -1.f);
}

// W~ row k of column n: k<100 -> W_h, 100..108 -> W_x, 109 -> b_lstm, else 0.
__device__ __forceinline__ float wld(int k, int n,
                                     const float* __restrict__ Wh,
                                     const float* __restrict__ Wx,
                                     const float* __restrict__ bl) {
  if (k < 100)  return Wh[k * 400 + n];
  if (k < 109)  return Wx[(k - 100) * 400 + n];
  if (k == 109) return bl[n];
  return 0.f;
}

__global__ __launch_bounds__(NTHR, 2)
void lstm_fused(const float* __restrict__ g_input,
                const float* __restrict__ g_task,
                const float* __restrict__ g_Win,
                const float* __restrict__ g_bin,
                const float* __restrict__ g_Wtask,
                const float* __restrict__ g_btask,
                const float* __restrict__ g_Wx,
                const float* __restrict__ g_Wh,
                const float* __restrict__ g_bl,
                const float* __restrict__ g_Wout,
                const float* __restrict__ g_bout,
                float* __restrict__ g_out)
{
  __shared__ SM L;
  const int tid  = threadIdx.x;
  const int bg0  = blockIdx.x * 4;
  const int wv   = tid >> 6;        // wave id 0..7
  const int lane = tid & 63;
  const int q    = lane >> 4;       // MFMA k-chunk quad
  const int nl   = lane & 15;       // n-within-tile (B) / m=batch row (A)

  // ---- cooperative LDS fill: Y = 0 except k==109 -> 1.0 (bias slot) ----
  for (int i = tid; i < 2 * 16 * 136; i += NTHR)
    ((_Float16*)L.Y)[i] = ((i % 136) == 109) ? (_Float16)1.f : (_Float16)0.f;
  for (int i = tid; i < 81; i += NTHR) { L.w_in[i] = g_Win[i]; L.w_task[i] = g_Wtask[i]; }
  if (tid < 9) { L.b_in[tid] = g_bin[tid]; L.b_task[tid] = g_btask[tid]; }

  // ---- MFMA tile ownership (waves 0..6): 25 N-tiles, clamped dups benign ----
  const int tbase = (wv < 4) ? wv * 4 : 16 + 3 * (wv - 4);

  // ---- B-fragments: W~[128,400] f16, weight-stationary (waves 0..6) ----
  half8 Bf[4][4];   // [ti][kc]; lane holds B[k=32kc+8q+j][n=16*tile+nl]
  if (wv < 7) {
#pragma unroll
    for (int ti = 0; ti < 4; ++ti) {
      const int tile = min(tbase + ti, 24);
      const int n = tile * 16 + nl;
#pragma unroll
      for (int kc = 0; kc < 4; ++kc) {
#pragma unroll
        for (int j = 0; j < 8; ++j)
          Bf[ti][kc][j] = (_Float16)wld(kc * 32 + q * 8 + j, n, g_Wh, g_Wx, g_bl);
      }
    }
  }

  // ---- wave-7 roles: proj (lanes 0..35) / staging (lanes 36..63) ----
  const int el = tid - 448;                         // wave-7 lane
  const int eb = (el >= 0 && el < 36) ? el / 9 : 0;
  const int od = (el >= 0 && el < 36) ? el % 9 : 0;
  const int sl = tid - 484;                         // staging lane 0..27
  const int sbA = (sl >= 0) ? sl / 9 : 0, sfA = (sl >= 0) ? sl % 9 : 0;   // item A
  const int jB  = sl + 28;                                                 // item B (sl<8)
  const int sbB = (jB < 36) ? jB / 9 : 0, sfB = (jB < 36) ? jB % 9 : 0;
  h2 wout[50];
  float breg = 0.f;
  if (wv == 7 && el < 36) {
#pragma unroll
    for (int j = 0; j < 50; ++j) {
      h2 h; h.x = (_Float16)g_Wout[(2 * j) * 9 + od];
      h.y = (_Float16)g_Wout[(2 * j + 1) * 9 + od];
      wout[j] = h;
    }
    breg = g_bout[od];
  }

  // ---- activation role: thread tid<400 owns (g = tid>>2, b = tid&3) ----
  const int ag = tid >> 2, ab = tid & 3;
  float c_state = 0.f;

  // staging prefetch ping-pong: raw row r lives in buf[r&1]
  float bufA[2][9], bufB[2][9];

  __syncthreads();

  // ---- prologue: encode s_0 -> Y[0]; prefetch raw rows 1 and 2 ----
  if (tid >= 484) {
#pragma unroll 1
    for (int pass = 0; pass < 2; ++pass) {
      const int j = sl + pass * 28;
      if (j < 36) {
        const int b = j / 9, f = j % 9;
        const float* src = g_input + (long)(bg0 + b) * 512 * 9;
        float a = L.b_in[f];
#pragma unroll
        for (int ff = 0; ff < 9; ++ff) a = fmaf(src[ff], L.w_in[ff * 9 + f], a);
        L.Y[0][b][100 + f] = (_Float16)fmaxf(a, 0.f);
      }
    }
#pragma unroll
    for (int r = 1; r <= 2; ++r) {
      const float* srcA = g_input + ((long)(bg0 + sbA) * 512 + r) * 9;
#pragma unroll
      for (int ff = 0; ff < 9; ++ff) bufA[r & 1][ff] = srcA[ff];
      if (sl < 8) {
        const float* srcB = g_input + ((long)(bg0 + sbB) * 512 + r) * 9;
#pragma unroll
        for (int ff = 0; ff < 9; ++ff) bufB[r & 1][ff] = srcB[ff];
      }
    }
  }
  __syncthreads();

  // ---- main recurrence: 2 barriers/step ----
  for (int t = 0; t < 576; ++t) {
    const int p = t & 1;
    // ---------- phase 1: MFMA -> Z (waves 0..6) | projection (wave 7) ----------
    if (wv < 7) {
      half8 A[4];
#pragma unroll
      for (int kc = 0; kc < 4; ++kc)
        A[kc] = *(const half8*)&L.Y[p][nl][kc * 32 + q * 8];
      f32x4 acc[4];
#pragma unroll
      for (int ti = 0; ti < 4; ++ti) {
        acc[ti] = (f32x4)0.f;
#pragma unroll
        for (int kc = 0; kc < 4; ++kc)
          acc[ti] = __builtin_amdgcn_mfma_f32_16x16x32_f16(A[kc], Bf[ti][kc], acc[ti], 0, 0, 0);
      }
      if (lane < 16) {
#pragma unroll
        for (int ti = 0; ti < 4; ++ti) {
          const int tile = min(tbase + ti, 24);
          *(f32x4*)&L.Z[tile * 16 + nl][0] = acc[ti];   // regs 0..3 = batches 0..3
        }
      }
    } else if (el < 36) {
      if (t > 0) {  // projection + softmax for step t-1 (h[t-1] in Y[p])
        const _Float16* yr = &L.Y[p][eb][0];
        float l0 = breg, l1 = 0.f, l2 = 0.f, l3 = 0.f;
#pragma unroll
        for (int j = 0; j < 12; ++j) {
          const h8v v = *(const h8v*)(yr + 8 * j);
          l0 = dot2(wout[4 * j + 0], __builtin_shufflevector(v, v, 0, 1), l0);
          l1 = dot2(wout[4 * j + 1], __builtin_shufflevector(v, v, 2, 3), l1);
          l2 = dot2(wout[4 * j + 2], __builtin_shufflevector(v, v, 4, 5), l2);
          l3 = dot2(wout[4 * j + 3], __builtin_shufflevector(v, v, 6, 7), l3);
        }
        const h4v tail = *(const h4v*)(yr + 96);
        l0 = dot2(wout[48], __builtin_shufflevector(tail, tail, 0, 1), l0);
        l1 = dot2(wout[49], __builtin_shufflevector(tail, tail, 2, 3), l1);
        const float lg = (l0 + l1) + (l2 + l3);
        const int lane0 = eb * 9;
        float m = lg;
#pragma unroll
        for (int j = 0; j < 9; ++j) m = fmaxf(m, __shfl(lg, lane0 + j, 64));
        const float e = __expf(lg - m);
        float ssum = 0.f;
#pragma unroll
        for (int j = 0; j < 9; ++j) ssum += __shfl(e, lane0 + j, 64);
        g_out[((long)(bg0 + eb) * 576 + (t - 1)) * 9 + od] = e * __builtin_amdgcn_rcpf(ssum);
      }
    }
    __syncthreads();
    // ---------- phase 2: activations (tid<400) | staging (wave-7 hi lanes) ----------
    if (tid < 400) {
      const float zi = L.Z[ag][ab];
      const float zf = L.Z[100 + ag][ab];
      const float zg = L.Z[200 + ag][ab];
      const float zo = L.Z[300 + ag][ab];
      const float gi = fast_sigmoid(zi);
      const float gf = fast_sigmoid(zf);
      const float gg = fast_tanh(zg);
      const float go = fast_sigmoid(zo);
      c_state = fmaf(gf, c_state, gi * gg);
      L.Y[p ^ 1][ab][ag] = (_Float16)(go * fast_tanh(c_state));
    } else if (tid >= 484) {
      const int rr = t + 1;          // row to encode (from regs, no global wait)
      if (rr < 576) {
        const float* wm = (rr < 512) ? L.w_in : L.w_task;
        const float* bm = (rr < 512) ? L.b_in : L.b_task;
        {
          float a = bm[sfA];
#pragma unroll
          for (int ff = 0; ff < 9; ++ff) a = fmaf(bufA[rr & 1][ff], wm[ff * 9 + sfA], a);
          L.Y[rr & 1][sbA][100 + sfA] = (_Float16)fmaxf(a, 0.f);
        }
        if (sl < 8) {
          float a = bm[sfB];
#pragma unroll
          for (int ff = 0; ff < 9; ++ff) a = fmaf(bufB[rr & 1][ff], wm[ff * 9 + sfB], a);
          L.Y[rr & 1][sbB][100 + sfB] = (_Float16)fmaxf(a, 0.f);
        }
      }
      const int rp = t + 3;          // row to prefetch (consumed at step t+2)
      if (rp < 576) {
        const float* srcA = (rp < 512) ? g_input + ((long)(bg0 + sbA) * 512 + rp) * 9
                                       : g_task  + ((long)(bg0 + sbA) * 64 + (rp - 512)) * 9;
#pragma unroll
        for (int ff = 0; ff < 9; ++ff) bufA[rp & 1][ff] = srcA[ff];
        if (sl < 8) {
          const float* srcB = (rp < 512) ? g_input + ((long)(bg0 + sbB) * 512 + rp) * 9
                                         : g_task  + ((long)(bg0 + sbB) * 64 + (rp - 512)) * 9;
#pragma unroll
          for (int ff = 0; ff < 9; ++ff) bufB[rp & 1][ff] = srcB[ff];
        }
      }
    }
    __syncthreads();
  }

  // ---- tail: projection for t=575 (h[575] in Y[0]) ----
  if (wv == 7 && el < 36) {
    const _Float16* yr = &L.Y[0][eb][0];
    float l0 = breg, l1 = 0.f, l2 = 0.f, l3 = 0.f;
#pragma unroll
    for (int j = 0; j < 12; ++j) {
      const h8v v = *(const h8v*)(yr + 8 * j);
      l0 = dot2(wout[4 * j + 0], __builtin_shufflevector(v, v, 0, 1), l0);
      l1 = dot2(wout[4 * j + 1], __builtin_shufflevector(v, v, 2, 3), l1);
      l2 = dot2(wout[4 * j + 2], __builtin_shufflevector(v, v, 4, 5), l2);
      l3 = dot2(wout[4 * j + 3], __builtin_shufflevector(v, v, 6, 7), l3);
    }
    const h4v tail = *(const h4v*)(yr + 96);
    l0 = dot2(wout[48], __builtin_shufflevector(tail, tail, 0, 1), l0);
    l1 = dot2(wout[49], __builtin_shufflevector(tail, tail, 2, 3), l1);
    const float lg = (l0 + l1) + (l2 + l3);
    const int lane0 = eb * 9;
    float m = lg;
#pragma unroll
    for (int j = 0; j < 9; ++j) m = fmaxf(m, __shfl(lg, lane0 + j, 64));
    const float e = __expf(lg - m);
    float ssum = 0.f;
#pragma unroll
    for (int j = 0; j < 9; ++j) ssum += __shfl(e, lane0 + j, 64);
    g_out[((long)(bg0 + eb) * 576 + 575) * 9 + od] = e * __builtin_amdgcn_rcpf(ssum);
  }
}

extern "C" void kernel_launch(void* const* d_in, const int* in_sizes, int n_in,
                              void* d_out, int out_size, void* d_ws, size_t ws_size,
                              hipStream_t stream) {
  const float* input  = (const float*)d_in[0];
  const float* task   = (const float*)d_in[1];
  const float* W_in   = (const float*)d_in[2];
  const float* b_in   = (const float*)d_in[3];
  const float* W_task = (const float*)d_in[4];
  const float* b_task = (const float*)d_in[5];
  const float* W_x    = (const float*)d_in[6];
  const float* W_h    = (const float*)d_in[7];
  const float* b_lstm = (const float*)d_in[8];
  const float* W_out  = (const float*)d_in[9];
  const float* b_out  = (const float*)d_in[10];
  float* out = (float*)d_out;

  lstm_fused<<<256, NTHR, 0, stream>>>(input, task, W_in, b_in, W_task, b_task,
                                       W_x, W_h, b_lstm, W_out, b_out, out);
}